// Round 9
// baseline (287.415 us; speedup 1.0000x reference)
//
#include <hip/hip_runtime.h>
#include <math.h>

#define B 4
#define NPTS 300000
#define G 15
#define G3 3375
#define PAIR_FLOATS (4*G3)       // 13500 floats: one (b,set) grid, 4 channels
#define SCENE_FLOATS (B*12*G3)   // 162000
#define RCHUNKS 42               // scatter blocks per (b,set): 42*12=504 blocks

typedef float v2f __attribute__((ext_vector_type(2)));

__device__ __forceinline__ float eluf(float v) {
    return v > 0.0f ? v : __expf(v) - 1.0f;
}

// memory-side RMW-as-load / RMW-as-store: XCD-coherent, no fences.
__device__ __forceinline__ float coh_load(const float* p) {
    return __hip_atomic_fetch_add((float*)p, 0.0f, __ATOMIC_RELAXED,
                                  __HIP_MEMORY_SCOPE_AGENT);
}
__device__ __forceinline__ void coh_store(float* p, float v) {
    __hip_atomic_exchange(p, v, __ATOMIC_RELAXED, __HIP_MEMORY_SCOPE_AGENT);
}

// ---------------------------------------------------------------------------
// Phase A: pure MLP, one point per thread (24-VGPR scalar-cache codegen).
// Spare duty on segment 0: zero stats (block 0,0,0) and scenes (y==0,z==0
// blocks) -- saves two memset/zero dispatches. Stream order guarantees both
// complete before scatter/conv1 read them.
// ---------------------------------------------------------------------------
__global__ __launch_bounds__(256)
void mlp_kernel(const float* __restrict__ P0,   // inputs  (set 0)
                const float* __restrict__ P1,   // goals   (set 1)
                const float* __restrict__ P2,   // backgrounds (set 2)
                const float* __restrict__ W1, const float* __restrict__ b1,
                const float* __restrict__ W2, const float* __restrict__ b2,
                const float* __restrict__ W3, const float* __restrict__ b3,
                float4* __restrict__ vals, unsigned short* __restrict__ cells,
                float* __restrict__ stats, float* __restrict__ scenes,
                int s0, int m)
{
    if (s0 == 0) {
        if (blockIdx.x == 0 && blockIdx.y == 0 && blockIdx.z == 0 &&
            threadIdx.x < 128)
            stats[threadIdx.x] = 0.0f;
        if (blockIdx.y == 0 && blockIdx.z == 0) {
            int t = blockIdx.x * 256 + threadIdx.x;
            if (t < SCENE_FLOATS) scenes[t] = 0.0f;
        }
    }

    int b   = blockIdx.y;
    int set = blockIdx.z;
    int i   = blockIdx.x * 256 + threadIdx.x;
    if (i >= m) return;
    const float* P = (set == 0) ? P0 : ((set == 1) ? P1 : P2);

    const float* p = P + ((size_t)b * NPTS + (size_t)(s0 + i)) * 3;
    float px = p[0], py = p[1], pz = p[2];

    const float HI = 14.9999f;  // GZ - 1e-4
    float cx = floorf(fminf(fmaxf(px, 0.0f), HI));
    float cy = floorf(fminf(fmaxf(py, 0.0f), HI));
    float cz = floorf(fminf(fmaxf(pz, 0.0f), HI));

    float x[12];
    x[0] = px - (cx + 0.5f); x[1] = py - (cy + 0.5f); x[2] = pz - (cz + 0.5f);
    x[3] = px - cx;          x[4] = py - cy;          x[5] = pz - cz;
    x[6] = px - (cx + 1.0f); x[7] = py - (cy + 1.0f); x[8] = pz - (cz + 1.0f);
    x[9]  = sqrtf(x[0]*x[0] + x[1]*x[1] + x[2]*x[2]);
    x[10] = sqrtf(x[3]*x[3] + x[4]*x[4] + x[5]*x[5]);
    x[11] = sqrtf(x[6]*x[6] + x[7]*x[7] + x[8]*x[8]);

    const v2f* W1v = (const v2f*)W1;   // [12][8] pairs
    const v2f* W2v = (const v2f*)W2;   // [16][8] pairs
    const v2f* W3v = (const v2f*)W3;   // [16][2] pairs
    const v2f* b1v = (const v2f*)b1;
    const v2f* b2v = (const v2f*)b2;
    const v2f* b3v = (const v2f*)b3;

    float h1[16];
#pragma unroll
    for (int j2 = 0; j2 < 8; ++j2) {
        v2f s = b1v[j2];
#pragma unroll
        for (int k = 0; k < 12; ++k) {
            v2f xb; xb.x = x[k]; xb.y = x[k];
            s = xb * W1v[k * 8 + j2] + s;
        }
        h1[2*j2]   = eluf(s.x);
        h1[2*j2+1] = eluf(s.y);
    }
    float h2[16];
#pragma unroll
    for (int j2 = 0; j2 < 8; ++j2) {
        v2f s = b2v[j2];
#pragma unroll
        for (int k = 0; k < 16; ++k) {
            v2f xb; xb.x = h1[k]; xb.y = h1[k];
            s = xb * W2v[k * 8 + j2] + s;
        }
        h2[2*j2]   = eluf(s.x);
        h2[2*j2+1] = eluf(s.y);
    }
    v2f o01 = b3v[0], o23 = b3v[1];
#pragma unroll
    for (int k = 0; k < 16; ++k) {
        v2f xb; xb.x = h2[k]; xb.y = h2[k];
        o01 = xb * W3v[k * 2 + 0] + o01;
        o23 = xb * W3v[k * 2 + 1] + o23;
    }

    int cell = (((int)cx) * G + (int)cy) * G + (int)cz;
    int pair = b * 3 + set;
    vals [(size_t)pair * m + i] = make_float4(o01.x, o01.y, o23.x, o23.y);
    cells[(size_t)pair * m + i] = (unsigned short)cell;
}

// ---------------------------------------------------------------------------
// Phase B: scatter-max into a PRIVATE LDS grid (54 KB), then flush DIRECTLY
// into scenes with global atomicMax (memory-side, XCD-coherent) -- only
// non-zero cells. Replaces the replica buffers + reduce_kernel dispatch.
// grid: (RCHUNKS, B, 3); block 512.
// ---------------------------------------------------------------------------
__global__ __launch_bounds__(512)
void scatter_kernel(const float4* __restrict__ vals,
                    const unsigned short* __restrict__ cells,
                    float* __restrict__ scenes, int m)
{
    __shared__ unsigned sg[PAIR_FLOATS];   // uint-ordered positive floats

    int rep = blockIdx.x;
    int b   = blockIdx.y;
    int set = blockIdx.z;
    int pair = b * 3 + set;

    for (int i = threadIdx.x; i < PAIR_FLOATS; i += 512) sg[i] = 0u;
    __syncthreads();

    int chunk = (m + RCHUNKS - 1) / RCHUNKS;
    int start = rep * chunk;
    int end   = min(m, start + chunk);
    const float4*         v = vals  + (size_t)pair * m;
    const unsigned short* c = cells + (size_t)pair * m;

    for (int i = start + (int)threadIdx.x; i < end; i += 512) {
        float4 o = v[i];
        int cell = c[i];
        if (o.x > 0.0f) atomicMax(&sg[          cell], __float_as_uint(o.x));
        if (o.y > 0.0f) atomicMax(&sg[    G3 + cell], __float_as_uint(o.y));
        if (o.z > 0.0f) atomicMax(&sg[2 * G3 + cell], __float_as_uint(o.z));
        if (o.w > 0.0f) atomicMax(&sg[3 * G3 + cell], __float_as_uint(o.w));
    }
    __syncthreads();

    unsigned* dst = (unsigned*)scenes + (size_t)pair * PAIR_FLOATS;
    for (int i = threadIdx.x; i < PAIR_FLOATS; i += 512) {
        unsigned u = sg[i];
        if (u) atomicMax(dst + i, u);    // positive floats order like uints
    }
}

// ---------------------------------------------------------------------------
// conv1: scenes [B,12,15,15,15] -> y0 [B,8,8,8,8] (raw conv+bias) + stats0
// 768 threads (12 waves) = (ci, oh, ow); ONE ci per thread -> 125-FMA chain.
// grid: (b,co,od)=256 blocks.
// ---------------------------------------------------------------------------
__global__ __launch_bounds__(768)
void conv1_kernel(const float* __restrict__ scenes,
                  const float* __restrict__ w,    // [8,12,125]
                  const float* __restrict__ bias, // [8]
                  float* __restrict__ y, float* __restrict__ stats)
{
    __shared__ float sred[768];
    int bx = blockIdx.x;
    int od = bx & 7, co = (bx >> 3) & 7, b = bx >> 6;
    int tid = threadIdx.x;
    int ow = tid & 7, oh = (tid >> 3) & 7, ci = tid >> 6;   // ci in 0..11

    const float* sc = scenes + (size_t)(b * 12 + ci) * G3;
    const float* wc = w + (size_t)(co * 12 + ci) * 125;
    float s = 0.0f;
#pragma unroll
    for (int kd = 0; kd < 5; ++kd) {
        int id = od * 2 - 2 + kd;
        if ((unsigned)id >= (unsigned)G) continue;   // block-uniform
#pragma unroll
        for (int kh = 0; kh < 5; ++kh) {
            int ih = oh * 2 - 2 + kh;
            bool hok = (unsigned)ih < (unsigned)G;
#pragma unroll
            for (int kw = 0; kw < 5; ++kw) {
                int iw = ow * 2 - 2 + kw;
                if (hok && (unsigned)iw < (unsigned)G)
                    s = fmaf(sc[(id * G + ih) * G + iw], wc[kd*25 + kh*5 + kw], s);
            }
        }
    }
    sred[tid] = s;
    __syncthreads();
    if (tid < 64) {
        float tot = bias[co];
#pragma unroll
        for (int g2 = 0; g2 < 12; ++g2) tot += sred[g2 * 64 + tid];
        y[(size_t)(b * 8 + co) * 512 + od * 64 + tid] = tot;
        float sum = tot, sq = tot * tot;
#pragma unroll
        for (int o = 32; o > 0; o >>= 1) {
            sum += __shfl_down(sum, o, 64);
            sq  += __shfl_down(sq,  o, 64);
        }
        if (tid == 0) { atomicAdd(&stats[co], sum); atomicAdd(&stats[8 + co], sq); }
    }
}

// ---------------------------------------------------------------------------
// conv_s: BN(stats_in)+ELU on the fly, then 5^3 conv. 512 threads, one ci
// per thread (125-FMA chain). On the LAST layer, y is written memory-side
// (atomicExch) and the 256th block to arrive (counter, NO spinning) applies
// the final BN+ELU to outp -- replaces the bn_final dispatch.
// grid: (b,co,od)=256 blocks.
// ---------------------------------------------------------------------------
__global__ __launch_bounds__(512)
void conv_s_kernel(const float* __restrict__ yin,
                   const float* __restrict__ w,     // [8,8,125] this layer
                   const float* __restrict__ bias,  // [8]
                   const float* __restrict__ g, const float* __restrict__ bet,
                   const float* __restrict__ stats_in,
                   float* __restrict__ yout, float* __restrict__ stats_out,
                   const float* __restrict__ gN, const float* __restrict__ betN,
                   unsigned* __restrict__ cnt, float* __restrict__ outp,
                   int last)
{
    __shared__ float slab[8 * 5 * 144];   // [ci][kd][12][12], zero-padded
    __shared__ float sstat[16], sscale[8], sshift[8];
    __shared__ float sred[512];

    int bx = blockIdx.x;
    int od = bx & 7, co = (bx >> 3) & 7, b = bx >> 6;
    int tid = threadIdx.x;

    // 1. issue all raw y[b] loads immediately
    float raw[8];
#pragma unroll
    for (int k = 0; k < 8; ++k) {
        int r = k * 512 + tid;           // 0..4095 = ci*512 + id*64 + ih*8 + iw
        raw[k] = yin[((size_t)(b * 8) << 9) + r];
    }

    // 2. stats -> LDS; 3. zero slab (overlap the loads)
    if (tid < 16) sstat[tid] = stats_in[tid];
    for (int i = tid; i < 5760; i += 512) slab[i] = 0.0f;
    __syncthreads();

    if (tid < 8) {
        float S = sstat[tid], Q = sstat[8 + tid];
        float m  = S * (1.0f / 2048.0f);
        float vv = Q * (1.0f / 2048.0f) - m * m;
        float rs = rsqrtf(vv + 1e-5f);
        float sc = g[tid] * rs;
        sscale[tid] = sc;
        sshift[tid] = bet[tid] - m * sc;
    }
    __syncthreads();

    // 4. scatter BN+ELU'd values into the padded slab
#pragma unroll
    for (int k = 0; k < 8; ++k) {
        int r  = k * 512 + tid;
        int ci = r >> 9, rem = r & 511;
        int id = rem >> 6, ih = (rem >> 3) & 7, iw = rem & 7;
        int kd = id - od + 2;
        if ((unsigned)kd < 5u) {
            float t = fmaf(raw[k], sscale[ci], sshift[ci]);
            slab[ci * 720 + kd * 144 + (ih + 2) * 12 + (iw + 2)] =
                t > 0.0f ? t : __expf(t) - 1.0f;
        }
    }
    __syncthreads();

    // 5. conv: thread = (ow, oh, ci); one ci each
    int ow = tid & 7, oh = (tid >> 3) & 7, ci = tid >> 6;
    const float* sl = slab + ci * 720;
    const float* wc = w + (size_t)(co * 8 + ci) * 125;
    float s = 0.0f;
#pragma unroll
    for (int kd = 0; kd < 5; ++kd) {
#pragma unroll
        for (int kh = 0; kh < 5; ++kh) {
            const float* row = sl + kd * 144 + (oh + kh) * 12 + ow;
            const float* wr = wc + kd * 25 + kh * 5;
#pragma unroll
            for (int kw = 0; kw < 5; ++kw) s = fmaf(row[kw], wr[kw], s);
        }
    }
    sred[tid] = s;
    __syncthreads();
    if (tid < 64) {
        float tot = bias[co];
#pragma unroll
        for (int g2 = 0; g2 < 8; ++g2) tot += sred[g2 * 64 + tid];
        size_t oidx = ((size_t)(b * 8 + co) << 9) + od * 64 + tid;
        if (last) coh_store(yout + oidx, tot);   // memory-side: finisher-visible
        else      yout[oidx] = tot;
        float sum = tot, sq = tot * tot;
#pragma unroll
        for (int o = 32; o > 0; o >>= 1) {
            sum += __shfl_down(sum, o, 64);
            sq  += __shfl_down(sq,  o, 64);
        }
        if (tid == 0) { atomicAdd(&stats_out[co], sum); atomicAdd(&stats_out[8 + co], sq); }
    }

    if (!last) return;

    // ---- finisher: last block to arrive applies final BN+ELU (no spinning) --
    __syncthreads();   // drains vmcnt(0): this block's coh_stores + stats ACK'd
    __shared__ unsigned amLast;
    if (tid == 0) {
        unsigned old = __hip_atomic_fetch_add(cnt, 1u, __ATOMIC_RELAXED,
                                              __HIP_MEMORY_SCOPE_AGENT);
        amLast = (old == 255u) ? 1u : 0u;
    }
    __syncthreads();
    if (!amLast) return;

    __shared__ float fsc[8], fsh[8];
    if (tid < 8) {
        float S = coh_load(stats_out + tid);
        float Q = coh_load(stats_out + 8 + tid);
        float mm = S * (1.0f / 2048.0f);
        float vv = Q * (1.0f / 2048.0f) - mm * mm;
        float rs = rsqrtf(vv + 1e-5f);
        float sc2 = gN[tid] * rs;
        fsc[tid] = sc2;
        fsh[tid] = betN[tid] - mm * sc2;
    }
    __syncthreads();
    for (int i2 = tid; i2 < 16384; i2 += 512) {
        float v = coh_load(yout + i2);           // memory-side readback
        int c = (i2 >> 9) & 7;
        float t = fmaf(v, fsc[c], fsh[c]);
        outp[i2] = t > 0.0f ? t : __expf(t) - 1.0f;
    }
}

// ---------------------------------------------------------------------------
extern "C" void kernel_launch(void* const* d_in, const int* in_sizes, int n_in,
                              void* d_out, int out_size, void* d_ws, size_t ws_size,
                              hipStream_t stream)
{
    const float* goals       = (const float*)d_in[0];
    const float* inputs      = (const float*)d_in[1];
    const float* backgrounds = (const float*)d_in[2];
    const float* W1 = (const float*)d_in[3];
    const float* b1 = (const float*)d_in[4];
    const float* W2 = (const float*)d_in[5];
    const float* b2 = (const float*)d_in[6];
    const float* W3 = (const float*)d_in[7];
    const float* b3 = (const float*)d_in[8];
    const float* conv1_w = (const float*)d_in[9];
    const float* conv1_b = (const float*)d_in[10];
    const float* bn1_g   = (const float*)d_in[11];
    const float* bn1_b   = (const float*)d_in[12];
    const float* convs_w = (const float*)d_in[13];
    const float* convs_b = (const float*)d_in[14];
    const float* bns_g   = (const float*)d_in[15];
    const float* bns_b   = (const float*)d_in[16];

    // --- pick S segments so the point stream fits the workspace -------------
    // floats: 48*Mseg (vals) + 6*Mseg (cells u16) + SCENE + 2*16384 + 128
    long ws_floats = (long)(ws_size / 4);
    long fixed = SCENE_FLOATS + 2L * 16384 + 128;
    int S = 64;
    for (int ps = 1; ps <= 64; ps *= 2) {
        long mseg = (NPTS + ps - 1) / ps;
        if (54L * mseg + fixed <= ws_floats) { S = ps; break; }
    }
    int Mseg = (NPTS + S - 1) / S;

    float*          wsp     = (float*)d_ws;
    float4*         vals    = (float4*)wsp;                       // 12*Mseg float4
    unsigned short* cells   = (unsigned short*)(wsp + 48L * Mseg);// 12*Mseg u16
    float*          scenes  = wsp + 54L * Mseg;                   // 162000
    float*          yA      = scenes + SCENE_FLOATS;              // 16384
    float*          yB      = yA + 16384;                         // 16384
    float*          stats   = yB + 16384;                         // 112 + cnt
    unsigned*       cnt     = (unsigned*)(stats + 116);           // within zeroed 128

    for (int s = 0; s < S; ++s) {
        int s0 = s * Mseg;
        int m  = min(Mseg, NPTS - s0);
        dim3 agrid((m + 255) / 256, B, 3);
        mlp_kernel<<<agrid, 256, 0, stream>>>(inputs, goals, backgrounds,
                                              W1, b1, W2, b2, W3, b3,
                                              vals, cells, stats, scenes, s0, m);
        dim3 bgrid(RCHUNKS, B, 3);
        scatter_kernel<<<bgrid, 512, 0, stream>>>(vals, cells, scenes, m);
    }

    conv1_kernel<<<256, 768, 0, stream>>>(scenes, conv1_w, conv1_b, yA, stats);

    const float* cur = yA;
    float* nxt = yB;
    for (int i = 0; i < 6; ++i) {
        const float* g   = (i == 0) ? bn1_g : (bns_g + (i - 1) * 8);
        const float* bet = (i == 0) ? bn1_b : (bns_b + (i - 1) * 8);
        conv_s_kernel<<<256, 512, 0, stream>>>(
            cur, convs_w + (size_t)i * 8000, convs_b + i * 8,
            g, bet, stats + i * 16, nxt, stats + (i + 1) * 16,
            bns_g + 5 * 8, bns_b + 5 * 8, cnt, (float*)d_out,
            (i == 5) ? 1 : 0);
        const float* tmp = cur; cur = nxt; nxt = (float*)tmp;
    }
}

// Round 10
// 278.217 us; speedup vs baseline: 1.0331x; 1.0331x over previous
//
#include <hip/hip_runtime.h>
#include <math.h>

#define B 4
#define NPTS 300000
#define G 15
#define G3 3375
#define PAIR_FLOATS (4*G3)       // 13500 floats: one (b,set) grid, 4 channels
#define SCENE_FLOATS (B*12*G3)   // 162000

typedef float v2f __attribute__((ext_vector_type(2)));

__device__ __forceinline__ float eluf(float v) {
    return v > 0.0f ? v : __expf(v) - 1.0f;
}

// ---------------------------------------------------------------------------
// prep: fold W1 rows using off_l = off_c + 0.5, off_u = off_c - 0.5:
//   W1f[d]   = W1[d] + W1[d+3] + W1[d+6]      (d = 0..2, the off_c rows)
//   W1f[3+d] = W1[9+d]                         (the norm rows)
//   b1f[j]   = b1[j] + 0.5*(W1[3..5][j] - W1[6..8][j] summed)
// Layer 1 then needs only 6 inputs (off_c, |off_c|, |off_l|, |off_u|).
// Also zeroes the stats buffer. 1 block, ~1us.
// ---------------------------------------------------------------------------
__global__ __launch_bounds__(128)
void prep_kernel(const float* __restrict__ W1, const float* __restrict__ b1,
                 float* __restrict__ W1f, float* __restrict__ b1f,
                 float* __restrict__ stats)
{
    int t = threadIdx.x;
    stats[t] = 0.0f;                       // 128 floats
    if (t < 16) {
        int j = t;
#pragma unroll
        for (int d = 0; d < 3; ++d) {
            W1f[d * 16 + j] = W1[d * 16 + j] + W1[(d + 3) * 16 + j]
                            + W1[(d + 6) * 16 + j];
            W1f[(3 + d) * 16 + j] = W1[(9 + d) * 16 + j];
        }
        float acc = 0.0f;
#pragma unroll
        for (int d = 0; d < 3; ++d)
            acc += W1[(d + 3) * 16 + j] - W1[(d + 6) * 16 + j];
        b1f[j] = b1[j] + 0.5f * acc;
    }
}

// ---------------------------------------------------------------------------
// Phase A: pure MLP, one point per thread (scalar-cache weight codegen).
// Layer 1 uses the FOLDED weights: 6 inputs x 16 = 96 FMAs (was 192), and
// the off_l/off_u norms come from |off_c|^2 +- s + 0.75 (s = sum off_c).
// ---------------------------------------------------------------------------
__global__ __launch_bounds__(256)
void mlp_kernel(const float* __restrict__ P0,   // inputs  (set 0)
                const float* __restrict__ P1,   // goals   (set 1)
                const float* __restrict__ P2,   // backgrounds (set 2)
                const float* __restrict__ W1f, const float* __restrict__ b1f,
                const float* __restrict__ W2, const float* __restrict__ b2,
                const float* __restrict__ W3, const float* __restrict__ b3,
                float4* __restrict__ vals, unsigned short* __restrict__ cells,
                int s0, int m)
{
    int b   = blockIdx.y;
    int set = blockIdx.z;
    int i   = blockIdx.x * 256 + threadIdx.x;
    if (i >= m) return;
    const float* P = (set == 0) ? P0 : ((set == 1) ? P1 : P2);

    const float* p = P + ((size_t)b * NPTS + (size_t)(s0 + i)) * 3;
    float px = p[0], py = p[1], pz = p[2];

    const float HI = 14.9999f;  // GZ - 1e-4
    float cx = floorf(fminf(fmaxf(px, 0.0f), HI));
    float cy = floorf(fminf(fmaxf(py, 0.0f), HI));
    float cz = floorf(fminf(fmaxf(pz, 0.0f), HI));

    float ox = px - (cx + 0.5f);
    float oy = py - (cy + 0.5f);
    float oz = pz - (cz + 0.5f);
    float nc2 = ox*ox + oy*oy + oz*oz;
    float s3  = ox + oy + oz;
    float in6[6];
    in6[0] = ox; in6[1] = oy; in6[2] = oz;
    in6[3] = sqrtf(nc2);                     // |off_c|
    in6[4] = sqrtf(nc2 + s3 + 0.75f);        // |off_l|
    in6[5] = sqrtf(nc2 - s3 + 0.75f);        // |off_u|

    // layer 1 (folded): 6 -> 16, 96 FMAs
    float h1[16];
#pragma unroll
    for (int j = 0; j < 16; ++j) {
        float s = b1f[j];
#pragma unroll
        for (int k = 0; k < 6; ++k) s = fmaf(in6[k], W1f[k * 16 + j], s);
        h1[j] = eluf(s);
    }

    const v2f* W2v = (const v2f*)W2;   // [16][8] pairs
    const v2f* W3v = (const v2f*)W3;   // [16][2] pairs
    const v2f* b2v = (const v2f*)b2;
    const v2f* b3v = (const v2f*)b3;

    float h2[16];
#pragma unroll
    for (int j2 = 0; j2 < 8; ++j2) {
        v2f s = b2v[j2];
#pragma unroll
        for (int k = 0; k < 16; ++k) {
            v2f xb; xb.x = h1[k]; xb.y = h1[k];
            s = xb * W2v[k * 8 + j2] + s;
        }
        h2[2*j2]   = eluf(s.x);
        h2[2*j2+1] = eluf(s.y);
    }
    v2f o01 = b3v[0], o23 = b3v[1];
#pragma unroll
    for (int k = 0; k < 16; ++k) {
        v2f xb; xb.x = h2[k]; xb.y = h2[k];
        o01 = xb * W3v[k * 2 + 0] + o01;
        o23 = xb * W3v[k * 2 + 1] + o23;
    }

    int cell = (((int)cx) * G + (int)cy) * G + (int)cz;
    int pair = b * 3 + set;
    vals [(size_t)pair * m + i] = make_float4(o01.x, o01.y, o23.x, o23.y);
    cells[(size_t)pair * m + i] = (unsigned short)cell;
}

// ---------------------------------------------------------------------------
// Phase B: scatter-max into a PRIVATE LDS grid (54 KB), flush with plain
// stores into this block's replica. 512 threads for latency hiding.
// grid: (K, B, 3); block 512.
// ---------------------------------------------------------------------------
__global__ __launch_bounds__(512)
void scatter_kernel(const float4* __restrict__ vals,
                    const unsigned short* __restrict__ cells,
                    float* __restrict__ scenesR, int K, int m, int carry)
{
    __shared__ unsigned sg[PAIR_FLOATS];   // uint-ordered positive floats

    int rep = blockIdx.x;
    int b   = blockIdx.y;
    int set = blockIdx.z;
    int pair = b * 3 + set;
    float* myrep = scenesR + ((size_t)pair * K + rep) * PAIR_FLOATS;

    if (carry) {
        for (int i = threadIdx.x; i < PAIR_FLOATS; i += 512)
            sg[i] = __float_as_uint(myrep[i]);     // values are >= 0
    } else {
        for (int i = threadIdx.x; i < PAIR_FLOATS; i += 512)
            sg[i] = 0u;
    }
    __syncthreads();

    int chunk = (m + K - 1) / K;
    int start = rep * chunk;
    int end   = min(m, start + chunk);
    const float4*         v = vals  + (size_t)pair * m;
    const unsigned short* c = cells + (size_t)pair * m;

    for (int i = start + (int)threadIdx.x; i < end; i += 512) {
        float4 o = v[i];
        int cell = c[i];
        if (o.x > 0.0f) atomicMax(&sg[          cell], __float_as_uint(o.x));
        if (o.y > 0.0f) atomicMax(&sg[    G3 + cell], __float_as_uint(o.y));
        if (o.z > 0.0f) atomicMax(&sg[2 * G3 + cell], __float_as_uint(o.z));
        if (o.w > 0.0f) atomicMax(&sg[3 * G3 + cell], __float_as_uint(o.w));
    }
    __syncthreads();

    for (int i = threadIdx.x; i < PAIR_FLOATS; i += 512)
        myrep[i] = __uint_as_float(sg[i]);
}

// ---------------------------------------------------------------------------
// max-reduce K replicas per pair -> scenes [B,12,G3]
// ---------------------------------------------------------------------------
__global__ __launch_bounds__(256)
void reduce_kernel(const float* __restrict__ scenesR, float* __restrict__ scenes,
                   int K)
{
    int t = blockIdx.x * 256 + threadIdx.x;
    if (t >= SCENE_FLOATS) return;
    int pair = t / PAIR_FLOATS;
    int j    = t - pair * PAIR_FLOATS;
    const float* src = scenesR + (size_t)pair * K * PAIR_FLOATS + j;
    float mx = 0.0f;
    for (int r = 0; r < K; ++r)
        mx = fmaxf(mx, src[(size_t)r * PAIR_FLOATS]);
    scenes[t] = mx;
}

// ---------------------------------------------------------------------------
// conv1: scenes [B,12,15,15,15] -> y0 [B,8,8,8,8] (raw conv+bias) + stats0
// 768 threads (12 waves) = (ci, oh, ow); ONE ci per thread -> 125-FMA chain.
// grid: (b,co,od)=256 blocks.
// ---------------------------------------------------------------------------
__global__ __launch_bounds__(768)
void conv1_kernel(const float* __restrict__ scenes,
                  const float* __restrict__ w,    // [8,12,125]
                  const float* __restrict__ bias, // [8]
                  float* __restrict__ y, float* __restrict__ stats)
{
    __shared__ float sred[768];
    int bx = blockIdx.x;
    int od = bx & 7, co = (bx >> 3) & 7, b = bx >> 6;
    int tid = threadIdx.x;
    int ow = tid & 7, oh = (tid >> 3) & 7, ci = tid >> 6;   // ci in 0..11

    const float* sc = scenes + (size_t)(b * 12 + ci) * G3;
    const float* wc = w + (size_t)(co * 12 + ci) * 125;
    float s = 0.0f;
#pragma unroll
    for (int kd = 0; kd < 5; ++kd) {
        int id = od * 2 - 2 + kd;
        if ((unsigned)id >= (unsigned)G) continue;   // block-uniform
#pragma unroll
        for (int kh = 0; kh < 5; ++kh) {
            int ih = oh * 2 - 2 + kh;
            bool hok = (unsigned)ih < (unsigned)G;
#pragma unroll
            for (int kw = 0; kw < 5; ++kw) {
                int iw = ow * 2 - 2 + kw;
                if (hok && (unsigned)iw < (unsigned)G)
                    s = fmaf(sc[(id * G + ih) * G + iw], wc[kd*25 + kh*5 + kw], s);
            }
        }
    }
    sred[tid] = s;
    __syncthreads();
    if (tid < 64) {
        float tot = bias[co];
#pragma unroll
        for (int g2 = 0; g2 < 12; ++g2) tot += sred[g2 * 64 + tid];
        y[(size_t)(b * 8 + co) * 512 + od * 64 + tid] = tot;
        float sum = tot, sq = tot * tot;
#pragma unroll
        for (int o = 32; o > 0; o >>= 1) {
            sum += __shfl_down(sum, o, 64);
            sq  += __shfl_down(sq,  o, 64);
        }
        if (tid == 0) { atomicAdd(&stats[co], sum); atomicAdd(&stats[8 + co], sq); }
    }
}

// ---------------------------------------------------------------------------
// conv_s: BN(stats_in,g,beta)+ELU applied to yin on the fly, then 5^3 conv.
// 512 threads (8 waves) = (ci, oh, ow); ONE ci per thread -> 125-FMA chain.
// Raw y loads issued first; stats/rsqrt + slab-zero overlap under them.
// grid: (b,co,od)=256 blocks.
// ---------------------------------------------------------------------------
__global__ __launch_bounds__(512)
void conv_s_kernel(const float* __restrict__ yin,
                   const float* __restrict__ w,     // [8,8,125] this layer
                   const float* __restrict__ bias,  // [8]
                   const float* __restrict__ g, const float* __restrict__ bet,
                   const float* __restrict__ stats_in,
                   float* __restrict__ yout, float* __restrict__ stats_out)
{
    __shared__ float slab[8 * 5 * 144];   // [ci][kd][12][12], zero-padded
    __shared__ float sstat[16], sscale[8], sshift[8];
    __shared__ float sred[512];

    int bx = blockIdx.x;
    int od = bx & 7, co = (bx >> 3) & 7, b = bx >> 6;
    int tid = threadIdx.x;

    // 1. issue all raw y[b] loads immediately (no dependencies, no guards)
    float raw[8];
#pragma unroll
    for (int k = 0; k < 8; ++k) {
        int r = k * 512 + tid;           // 0..4095 = ci*512 + id*64 + ih*8 + iw
        raw[k] = yin[((size_t)(b * 8) << 9) + r];
    }

    // 2. stats -> LDS; 3. zero slab (both overlap the loads above)
    if (tid < 16) sstat[tid] = stats_in[tid];
    for (int i = tid; i < 5760; i += 512) slab[i] = 0.0f;
    __syncthreads();

    if (tid < 8) {
        float S = sstat[tid], Q = sstat[8 + tid];
        float m  = S * (1.0f / 2048.0f);
        float vv = Q * (1.0f / 2048.0f) - m * m;
        float rs = rsqrtf(vv + 1e-5f);
        float sc = g[tid] * rs;
        sscale[tid] = sc;
        sshift[tid] = bet[tid] - m * sc;
    }
    __syncthreads();

    // 4. scatter BN+ELU'd values into the padded slab
#pragma unroll
    for (int k = 0; k < 8; ++k) {
        int r  = k * 512 + tid;
        int ci = r >> 9, rem = r & 511;
        int id = rem >> 6, ih = (rem >> 3) & 7, iw = rem & 7;
        int kd = id - od + 2;
        if ((unsigned)kd < 5u) {
            float t = fmaf(raw[k], sscale[ci], sshift[ci]);
            slab[ci * 720 + kd * 144 + (ih + 2) * 12 + (iw + 2)] =
                t > 0.0f ? t : __expf(t) - 1.0f;
        }
    }
    __syncthreads();

    // 5. conv: thread = (ow, oh, ci); one ci each
    int ow = tid & 7, oh = (tid >> 3) & 7, ci = tid >> 6;
    const float* sl = slab + ci * 720;
    const float* wc = w + (size_t)(co * 8 + ci) * 125;
    float s = 0.0f;
#pragma unroll
    for (int kd = 0; kd < 5; ++kd) {
#pragma unroll
        for (int kh = 0; kh < 5; ++kh) {
            const float* row = sl + kd * 144 + (oh + kh) * 12 + ow;
            const float* wr = wc + kd * 25 + kh * 5;
#pragma unroll
            for (int kw = 0; kw < 5; ++kw) s = fmaf(row[kw], wr[kw], s);
        }
    }
    sred[tid] = s;
    __syncthreads();
    if (tid < 64) {
        float tot = bias[co];
#pragma unroll
        for (int g2 = 0; g2 < 8; ++g2) tot += sred[g2 * 64 + tid];
        yout[(size_t)(b * 8 + co) * 512 + od * 64 + tid] = tot;
        float sum = tot, sq = tot * tot;
#pragma unroll
        for (int o = 32; o > 0; o >>= 1) {
            sum += __shfl_down(sum, o, 64);
            sq  += __shfl_down(sq,  o, 64);
        }
        if (tid == 0) { atomicAdd(&stats_out[co], sum); atomicAdd(&stats_out[8 + co], sq); }
    }
}

// ---------------------------------------------------------------------------
// final BN + ELU -> d_out
// ---------------------------------------------------------------------------
__global__ __launch_bounds__(256)
void bn_final_kernel(const float* __restrict__ yin,
                     const float* __restrict__ g, const float* __restrict__ bet,
                     const float* __restrict__ stats_in, float* __restrict__ outp)
{
    int i = blockIdx.x * 256 + threadIdx.x;   // 16384 total
    float v = yin[i];                          // issue load first
    int c = (i >> 9) & 7;
    float S = stats_in[c], Q = stats_in[8 + c];
    float m  = S * (1.0f / 2048.0f);
    float vv = Q * (1.0f / 2048.0f) - m * m;
    float rs = rsqrtf(vv + 1e-5f);
    float sc = g[c] * rs;
    float sh = bet[c] - m * sc;
    float t = fmaf(v, sc, sh);
    outp[i] = t > 0.0f ? t : __expf(t) - 1.0f;
}

// ---------------------------------------------------------------------------
extern "C" void kernel_launch(void* const* d_in, const int* in_sizes, int n_in,
                              void* d_out, int out_size, void* d_ws, size_t ws_size,
                              hipStream_t stream)
{
    const float* goals       = (const float*)d_in[0];
    const float* inputs      = (const float*)d_in[1];
    const float* backgrounds = (const float*)d_in[2];
    const float* W1 = (const float*)d_in[3];
    const float* b1 = (const float*)d_in[4];
    const float* W2 = (const float*)d_in[5];
    const float* b2 = (const float*)d_in[6];
    const float* W3 = (const float*)d_in[7];
    const float* b3 = (const float*)d_in[8];
    const float* conv1_w = (const float*)d_in[9];
    const float* conv1_b = (const float*)d_in[10];
    const float* bn1_g   = (const float*)d_in[11];
    const float* bn1_b   = (const float*)d_in[12];
    const float* convs_w = (const float*)d_in[13];
    const float* convs_b = (const float*)d_in[14];
    const float* bns_g   = (const float*)d_in[15];
    const float* bns_b   = (const float*)d_in[16];

    // --- pick (K replicas, S segments) to fit the workspace -----------------
    // floats: 48*Mseg (vals) + 6*Mseg (cells u16) + K*SCENE + fixed
    long ws_floats = (long)(ws_size / 4);
    long fixed = SCENE_FLOATS + 2L * 16384 + 256;   // y bufs + stats + W1f/b1f
    static const int plans[][2] = {
        {42,1},{42,2},{42,4},{24,4},{21,6},{16,8},{8,12},{4,16},{2,32},{1,64}};
    int K = 1, S = 64;
    for (int pi = 0; pi < 10; ++pi) {
        int pk = plans[pi][0], ps = plans[pi][1];
        long mseg = (NPTS + ps - 1) / ps;
        long need = 54L * mseg + (long)pk * SCENE_FLOATS + fixed;
        if (need <= ws_floats) { K = pk; S = ps; break; }
    }
    int Mseg = (NPTS + S - 1) / S;

    float*          wsp     = (float*)d_ws;
    float4*         vals    = (float4*)wsp;                       // 12*Mseg float4
    unsigned short* cells   = (unsigned short*)(wsp + 48L * Mseg);// 12*Mseg u16
    float*          scenesR = wsp + 54L * Mseg;                   // K * SCENE_FLOATS
    float*          scenes  = scenesR + (size_t)K * SCENE_FLOATS; // 162000
    float*          yA      = scenes + SCENE_FLOATS;              // 16384
    float*          yB      = yA + 16384;                         // 16384
    float*          stats   = yB + 16384;                         // 128 floats
    float*          W1f     = stats + 128;                        // 96 floats
    float*          b1f     = W1f + 96;                           // 16 floats

    prep_kernel<<<1, 128, 0, stream>>>(W1, b1, W1f, b1f, stats);

    for (int s = 0; s < S; ++s) {
        int s0 = s * Mseg;
        int m  = min(Mseg, NPTS - s0);
        dim3 agrid((m + 255) / 256, B, 3);
        mlp_kernel<<<agrid, 256, 0, stream>>>(inputs, goals, backgrounds,
                                              W1f, b1f, W2, b2, W3, b3,
                                              vals, cells, s0, m);
        dim3 bgrid(K, B, 3);
        scatter_kernel<<<bgrid, 512, 0, stream>>>(vals, cells, scenesR, K, m,
                                                  s > 0 ? 1 : 0);
    }

    reduce_kernel<<<(SCENE_FLOATS + 255) / 256, 256, 0, stream>>>(scenesR, scenes, K);

    conv1_kernel<<<256, 768, 0, stream>>>(scenes, conv1_w, conv1_b, yA, stats);

    const float* cur = yA;
    float* nxt = yB;
    for (int i = 0; i < 6; ++i) {
        const float* g   = (i == 0) ? bn1_g : (bns_g + (i - 1) * 8);
        const float* bet = (i == 0) ? bn1_b : (bns_b + (i - 1) * 8);
        conv_s_kernel<<<256, 512, 0, stream>>>(
            cur, convs_w + (size_t)i * 8000, convs_b + i * 8,
            g, bet, stats + i * 16, nxt, stats + (i + 1) * 16);
        const float* tmp = cur; cur = nxt; nxt = (float*)tmp;
    }

    bn_final_kernel<<<64, 256, 0, stream>>>(cur, bns_g + 5 * 8, bns_b + 5 * 8,
                                            stats + 6 * 16, (float*)d_out);
}